// Round 1
// baseline (564.581 us; speedup 1.0000x reference)
//
#include <hip/hip_runtime.h>
#include <hip/hip_bf16.h>

// GraphSAGE 2-layer + linear head, N=100000 nodes, d=h=128, E=640000 edges.
// Pipeline per launch:
//   1. build CSR (deg count -> wave-scan offsets -> scatter src indices)
//   2. bufA = mean-agg(x)
//   3. bufB = relu(bufA@W1_l + x@W1_r + b1)
//   4. bufA = mean-agg(bufB)
//   5. bufA = relu(bufA@W2_l + bufB@W2_r + b2)   (in-place safe: block-local rows)
//   6. out  = bufA @ W_lin + b_lin

__global__ void k_count(const int* __restrict__ dst, int* __restrict__ deg, int E) {
    int e = blockIdx.x * blockDim.x + threadIdx.x;
    if (e < E) atomicAdd(&deg[dst[e]], 1);
}

// start[i] = exclusive running offset (unordered across waves, disjoint slices).
// One atomic per wave via shuffle prefix-scan.
__global__ void k_offsets(const int* __restrict__ deg, int* __restrict__ start,
                          int* __restrict__ fill, int* __restrict__ cursor, int n) {
    int i = blockIdx.x * blockDim.x + threadIdx.x;
    int lane = threadIdx.x & 63;
    int d = (i < n) ? deg[i] : 0;
    int v = d;
#pragma unroll
    for (int off = 1; off < 64; off <<= 1) {
        int t = __shfl_up(v, off);
        if (lane >= off) v += t;
    }
    int total = __shfl(v, 63);
    int base = 0;
    if (lane == 0) base = atomicAdd(cursor, total);
    base = __shfl(base, 0);
    if (i < n) {
        int s = base + v - d;   // exclusive
        start[i] = s;
        fill[i] = s;
    }
}

__global__ void k_scatter(const int* __restrict__ src, const int* __restrict__ dst,
                          int* __restrict__ fill, int* __restrict__ esrc, int E) {
    int e = blockIdx.x * blockDim.x + threadIdx.x;
    if (e < E) {
        int p = atomicAdd(&fill[dst[e]], 1);
        esrc[p] = src[e];
    }
}

// One wave per node: lane holds features [2*lane, 2*lane+1]; each neighbor row is
// one coalesced 512B load across the wave.
__global__ void k_aggregate(const float* __restrict__ feat, float* __restrict__ out,
                            const int* __restrict__ start, const int* __restrict__ deg,
                            const int* __restrict__ esrc, int n) {
    int wave = (int)((blockIdx.x * (size_t)blockDim.x + threadIdx.x) >> 6);
    int lane = threadIdx.x & 63;
    if (wave >= n) return;
    int s = start[wave];
    int d = deg[wave];
    float2 acc = make_float2(0.f, 0.f);
    for (int j = 0; j < d; ++j) {
        int src = esrc[s + j];
        float2 v = *(const float2*)(feat + (size_t)src * 128 + lane * 2);
        acc.x += v.x;
        acc.y += v.y;
    }
    float inv = 1.0f / (float)max(d, 1);
    *(float2*)(out + (size_t)wave * 128 + lane * 2) = make_float2(acc.x * inv, acc.y * inv);
}

// out[m0:m0+128, 0:128] = relu(A0@Wl + A1@Wr + bias)
// Treated as one GEMM with K=256 over the concatenated [A0|A1] / [Wl;Wr].
// 256 threads, 8x8 microtile each, K staged in LDS chunks of 16.
__launch_bounds__(256)
__global__ void k_layer(const float* __restrict__ A0, const float* __restrict__ A1,
                        const float* __restrict__ Wl, const float* __restrict__ Wr,
                        const float* __restrict__ bias, float* __restrict__ out,
                        int n, int do_relu) {
    __shared__ float As[16][128];
    __shared__ float Bs[16][128];
    int m0 = blockIdx.x * 128;
    int t = threadIdx.x;
    int r0 = (t >> 4) * 8;   // row within tile
    int c0 = (t & 15) * 8;   // col
    float acc[8][8] = {};

    int arow = t & 127;      // A-loader row
    int ahalf = t >> 7;      // which 8-k half of the 16-k chunk

    for (int k0 = 0; k0 < 256; k0 += 16) {
        // --- stage A chunk (transposed: As[kk][row]) ---
        {
            int k = k0 + ahalf * 8;
            const float* base = (k < 128) ? A0 : A1;
            int kk0 = k & 127;
            int grow = m0 + arow;
            float4 v0 = make_float4(0, 0, 0, 0), v1 = make_float4(0, 0, 0, 0);
            if (grow < n) {
                v0 = *(const float4*)(base + (size_t)grow * 128 + kk0);
                v1 = *(const float4*)(base + (size_t)grow * 128 + kk0 + 4);
            }
            int kb = ahalf * 8;
            As[kb + 0][arow] = v0.x; As[kb + 1][arow] = v0.y;
            As[kb + 2][arow] = v0.z; As[kb + 3][arow] = v0.w;
            As[kb + 4][arow] = v1.x; As[kb + 5][arow] = v1.y;
            As[kb + 6][arow] = v1.z; As[kb + 7][arow] = v1.w;
        }
        // --- stage B chunk: Bs[kk][col] = W[k0+kk][col] ---
        {
            int kk = t >> 4;
            int nc = (t & 15) * 8;
            int k = k0 + kk;
            const float* w = (k < 128) ? (Wl + (size_t)k * 128) : (Wr + (size_t)(k - 128) * 128);
            *(float4*)&Bs[kk][nc] = *(const float4*)(w + nc);
            *(float4*)&Bs[kk][nc + 4] = *(const float4*)(w + nc + 4);
        }
        __syncthreads();
#pragma unroll
        for (int kk = 0; kk < 16; ++kk) {
            float4 a0 = *(const float4*)&As[kk][r0];
            float4 a1 = *(const float4*)&As[kk][r0 + 4];
            float4 b0 = *(const float4*)&Bs[kk][c0];
            float4 b1 = *(const float4*)&Bs[kk][c0 + 4];
            float a[8] = {a0.x, a0.y, a0.z, a0.w, a1.x, a1.y, a1.z, a1.w};
            float b[8] = {b0.x, b0.y, b0.z, b0.w, b1.x, b1.y, b1.z, b1.w};
#pragma unroll
            for (int i = 0; i < 8; ++i)
#pragma unroll
                for (int j = 0; j < 8; ++j)
                    acc[i][j] += a[i] * b[j];
        }
        __syncthreads();
    }
    // epilogue
#pragma unroll
    for (int i = 0; i < 8; ++i) {
        int row = m0 + r0 + i;
        if (row >= n) continue;
#pragma unroll
        for (int j = 0; j < 8; ++j) {
            float v = acc[i][j] + bias[c0 + j];
            if (do_relu) v = fmaxf(v, 0.f);
            acc[i][j] = v;
        }
        *(float4*)(out + (size_t)row * 128 + c0) =
            make_float4(acc[i][0], acc[i][1], acc[i][2], acc[i][3]);
        *(float4*)(out + (size_t)row * 128 + c0 + 4) =
            make_float4(acc[i][4], acc[i][5], acc[i][6], acc[i][7]);
    }
}

// out[i] = dot(h[i,:], Wlin) + blin ; one wave per node.
__global__ void k_head(const float* __restrict__ h, const float* __restrict__ Wlin,
                       const float* __restrict__ blin, float* __restrict__ out, int n) {
    int wave = (int)((blockIdx.x * (size_t)blockDim.x + threadIdx.x) >> 6);
    int lane = threadIdx.x & 63;
    if (wave >= n) return;
    float2 v = *(const float2*)(h + (size_t)wave * 128 + lane * 2);
    float2 w = *(const float2*)(Wlin + lane * 2);
    float s = v.x * w.x + v.y * w.y;
#pragma unroll
    for (int off = 32; off > 0; off >>= 1) s += __shfl_down(s, off);
    if (lane == 0) out[wave] = s + blin[0];
}

extern "C" void kernel_launch(void* const* d_in, const int* in_sizes, int n_in,
                              void* d_out, int out_size, void* d_ws, size_t ws_size,
                              hipStream_t stream) {
    const float* x    = (const float*)d_in[0];
    const int*   edge = (const int*)d_in[1];    // [2, E] int
    const float* W1l  = (const float*)d_in[2];
    const float* b1   = (const float*)d_in[3];
    const float* W1r  = (const float*)d_in[4];
    const float* W2l  = (const float*)d_in[5];
    const float* b2   = (const float*)d_in[6];
    const float* W2r  = (const float*)d_in[7];
    const float* Wlin = (const float*)d_in[8];
    const float* blin = (const float*)d_in[9];
    float* out = (float*)d_out;

    int n = out_size;               // 100000 nodes
    int E = in_sizes[1] / 2;        // 640000 edges
    (void)n_in; (void)ws_size;

    char* ws = (char*)d_ws;
    size_t off = 0;
    auto take = [&](size_t bytes) -> char* {
        char* p = ws + off;
        off += (bytes + 255) & ~(size_t)255;
        return p;
    };
    int* deg    = (int*)take((size_t)n * 4);
    int* start  = (int*)take((size_t)n * 4);
    int* fill   = (int*)take((size_t)n * 4);
    int* cursor = (int*)take(256);
    int* esrc   = (int*)take((size_t)E * 4);
    float* bufA = (float*)take((size_t)n * 128 * 4);
    float* bufB = (float*)take((size_t)n * 128 * 4);

    hipMemsetAsync(deg, 0, (size_t)n * 4, stream);
    hipMemsetAsync(cursor, 0, 4, stream);

    const int* esrc_in = edge;       // row 0: src
    const int* edst_in = edge + E;   // row 1: dst

    k_count<<<(E + 255) / 256, 256, 0, stream>>>(edst_in, deg, E);
    k_offsets<<<(n + 255) / 256, 256, 0, stream>>>(deg, start, fill, cursor, n);
    k_scatter<<<(E + 255) / 256, 256, 0, stream>>>(esrc_in, edst_in, fill, esrc, E);

    int aggBlocks = (n + 3) / 4;     // 4 waves (nodes) per 256-thread block
    int gemmBlocks = (n + 127) / 128;

    // layer 1
    k_aggregate<<<aggBlocks, 256, 0, stream>>>(x, bufA, start, deg, esrc, n);
    k_layer<<<gemmBlocks, 256, 0, stream>>>(bufA, x, W1l, W1r, b1, bufB, n, 1);
    // layer 2
    k_aggregate<<<aggBlocks, 256, 0, stream>>>(bufB, bufA, start, deg, esrc, n);
    k_layer<<<gemmBlocks, 256, 0, stream>>>(bufA, bufB, W2l, W2r, b2, bufA, n, 1);
    // head
    k_head<<<aggBlocks, 256, 0, stream>>>(bufA, Wlin, blin, out, n);
}

// Round 2
// 414.225 us; speedup vs baseline: 1.3630x; 1.3630x over previous
//
#include <hip/hip_runtime.h>
#include <hip/hip_bf16.h>

// GraphSAGE 2-layer + linear head, N=100000 nodes, d=h=128, E=640000 edges.
// R2: GEMM layers moved to bf16 MFMA (v_mfma_f32_32x32x16_bf16, fp32 accum).
// Weights pre-transposed+converted once per launch (k_prepw); activations
// converted fp32->bf16 during LDS staging. Aggregation/head stay fp32.

#define ND 128          // feature dim
#define KTOT 256        // concat K ([agg | self])
#define BK 32           // K-chunk
#define ASTRIDE 40      // BK + 8 pad (shorts)

typedef __bf16 bf16x8 __attribute__((ext_vector_type(8)));
typedef float floatx16 __attribute__((ext_vector_type(16)));

__device__ inline unsigned short f2bf(float f) {
    union { float f; unsigned u; } v; v.f = f;
    unsigned r = v.u + 0x7fffu + ((v.u >> 16) & 1u);   // RTNE
    return (unsigned short)(r >> 16);
}

// ---------------- CSR build ----------------
__global__ void k_count(const int* __restrict__ dst, int* __restrict__ deg, int E) {
    int e = blockIdx.x * blockDim.x + threadIdx.x;
    if (e < E) atomicAdd(&deg[dst[e]], 1);
}

__global__ void k_offsets(const int* __restrict__ deg, int* __restrict__ start,
                          int* __restrict__ fill, int* __restrict__ cursor, int n) {
    int i = blockIdx.x * blockDim.x + threadIdx.x;
    int lane = threadIdx.x & 63;
    int d = (i < n) ? deg[i] : 0;
    int v = d;
#pragma unroll
    for (int off = 1; off < 64; off <<= 1) {
        int t = __shfl_up(v, off);
        if (lane >= off) v += t;
    }
    int total = __shfl(v, 63);
    int base = 0;
    if (lane == 0) base = atomicAdd(cursor, total);
    base = __shfl(base, 0);
    if (i < n) {
        int s = base + v - d;   // exclusive
        start[i] = s;
        fill[i] = s;
    }
}

__global__ void k_scatter(const int* __restrict__ src, const int* __restrict__ dst,
                          int* __restrict__ fill, int* __restrict__ esrc, int E) {
    int e = blockIdx.x * blockDim.x + threadIdx.x;
    if (e < E) {
        int p = atomicAdd(&fill[dst[e]], 1);
        esrc[p] = src[e];
    }
}

// ---------------- mean aggregation (one wave per node) ----------------
__global__ void k_aggregate(const float* __restrict__ feat, float* __restrict__ out,
                            const int* __restrict__ start, const int* __restrict__ deg,
                            const int* __restrict__ esrc, int n) {
    int wave = (int)((blockIdx.x * (size_t)blockDim.x + threadIdx.x) >> 6);
    int lane = threadIdx.x & 63;
    if (wave >= n) return;
    int s = start[wave];
    int d = deg[wave];
    float2 acc = make_float2(0.f, 0.f);
    for (int j = 0; j < d; ++j) {
        int src = esrc[s + j];
        float2 v = *(const float2*)(feat + (size_t)src * ND + lane * 2);
        acc.x += v.x;
        acc.y += v.y;
    }
    float inv = 1.0f / (float)max(d, 1);
    *(float2*)(out + (size_t)wave * ND + lane * 2) = make_float2(acc.x * inv, acc.y * inv);
}

// ---------------- weight prep: Wt[n][k] bf16 from [Wl;Wr] fp32 [k][n] ----------------
__global__ void k_prepw(const float* __restrict__ Wl, const float* __restrict__ Wr,
                        unsigned short* __restrict__ Wt) {
    int idx = blockIdx.x * blockDim.x + threadIdx.x;   // 0..32767
    int nn = idx >> 8;       // 0..127 (output col)
    int kk = idx & 255;      // 0..255 (concat K)
    float v = (kk < 128) ? Wl[(size_t)kk * ND + nn] : Wr[(size_t)(kk - 128) * ND + nn];
    Wt[(size_t)nn * KTOT + kk] = f2bf(v);
}

// ---------------- MFMA GEMM layer ----------------
// out[m0:m0+128, :] = relu([A0|A1] @ Wt^T + bias), K=256.
// 256 threads = 4 waves in 2x2 grid; each wave: 2x2 tiles of 32x32.
__launch_bounds__(256, 2)
__global__ void k_layer_mfma(const float* __restrict__ A0, const float* __restrict__ A1,
                             const unsigned short* __restrict__ Wt,
                             const float* __restrict__ bias, float* __restrict__ out,
                             int n, int do_relu) {
    __shared__ unsigned short As[128 * ASTRIDE];
    __shared__ unsigned short Bs[128 * ASTRIDE];
    const int t = threadIdx.x;
    const int m0 = blockIdx.x * 128;
    const int wave = t >> 6, lane = t & 63;
    const int l31 = lane & 31, lhalf = lane >> 5;
    const int wm = (wave >> 1) * 64;   // wave row offset within tile
    const int wn = (wave & 1) * 64;    // wave col offset

    floatx16 acc[2][2];
#pragma unroll
    for (int i = 0; i < 2; ++i)
#pragma unroll
        for (int j = 0; j < 2; ++j) acc[i][j] = (floatx16)0.0f;

    const int srow = t >> 1;           // staging row 0..127
    const int skid = (t & 1) * 16;     // staging k offset 0/16

    for (int kc = 0; kc < 8; ++kc) {
        const int k0 = kc * BK;
        // --- stage A chunk: As[row][k] bf16, converted from fp32 ---
        {
            const float* base = (k0 < 128) ? A0 : A1;
            const int col = (k0 & 127) + skid;
            const int grow = m0 + srow;
            float4 v0 = {0,0,0,0}, v1 = {0,0,0,0}, v2 = {0,0,0,0}, v3 = {0,0,0,0};
            if (grow < n) {
                const float4* p = (const float4*)(base + (size_t)grow * ND + col);
                v0 = p[0]; v1 = p[1]; v2 = p[2]; v3 = p[3];
            }
            unsigned short* a = &As[srow * ASTRIDE + skid];
            a[0] = f2bf(v0.x); a[1] = f2bf(v0.y); a[2]  = f2bf(v0.z); a[3]  = f2bf(v0.w);
            a[4] = f2bf(v1.x); a[5] = f2bf(v1.y); a[6]  = f2bf(v1.z); a[7]  = f2bf(v1.w);
            a[8] = f2bf(v2.x); a[9] = f2bf(v2.y); a[10] = f2bf(v2.z); a[11] = f2bf(v2.w);
            a[12]= f2bf(v3.x); a[13]= f2bf(v3.y); a[14] = f2bf(v3.z); a[15] = f2bf(v3.w);
        }
        // --- stage B chunk: Bs[n][k] <- Wt[n][k0+k] (already bf16) ---
        {
            const int4* p = (const int4*)(Wt + (size_t)srow * KTOT + k0 + skid);
            int4* q = (int4*)&Bs[srow * ASTRIDE + skid];
            q[0] = p[0];
            q[1] = p[1];
        }
        __syncthreads();
        // --- fragments + MFMA ---
        bf16x8 af[2][2], bfr[2][2];
#pragma unroll
        for (int mi = 0; mi < 2; ++mi)
#pragma unroll
            for (int ks = 0; ks < 2; ++ks)
                af[mi][ks] = *(const bf16x8*)&As[(wm + mi * 32 + l31) * ASTRIDE + ks * 16 + lhalf * 8];
#pragma unroll
        for (int ni = 0; ni < 2; ++ni)
#pragma unroll
            for (int ks = 0; ks < 2; ++ks)
                bfr[ni][ks] = *(const bf16x8*)&Bs[(wn + ni * 32 + l31) * ASTRIDE + ks * 16 + lhalf * 8];
#pragma unroll
        for (int mi = 0; mi < 2; ++mi)
#pragma unroll
            for (int ni = 0; ni < 2; ++ni) {
                acc[mi][ni] = __builtin_amdgcn_mfma_f32_32x32x16_bf16(af[mi][0], bfr[ni][0], acc[mi][ni], 0, 0, 0);
                acc[mi][ni] = __builtin_amdgcn_mfma_f32_32x32x16_bf16(af[mi][1], bfr[ni][1], acc[mi][ni], 0, 0, 0);
            }
        __syncthreads();
    }
    // --- epilogue: C/D layout col=lane&31, row=(reg&3)+8*(reg>>2)+4*(lane>>5) ---
#pragma unroll
    for (int mi = 0; mi < 2; ++mi)
#pragma unroll
        for (int ni = 0; ni < 2; ++ni) {
            const int c = wn + ni * 32 + l31;
            const float bv = bias[c];
#pragma unroll
            for (int r8 = 0; r8 < 4; ++r8)
#pragma unroll
                for (int r4 = 0; r4 < 4; ++r4) {
                    const int reg = r8 * 4 + r4;
                    const int row = m0 + wm + mi * 32 + lhalf * 4 + r4 + r8 * 8;
                    if (row < n) {
                        float v = acc[mi][ni][reg] + bv;
                        if (do_relu) v = fmaxf(v, 0.f);
                        out[(size_t)row * ND + c] = v;
                    }
                }
        }
}

// ---------------- head: out[i] = dot(h[i,:], Wlin) + blin ----------------
__global__ void k_head(const float* __restrict__ h, const float* __restrict__ Wlin,
                       const float* __restrict__ blin, float* __restrict__ out, int n) {
    int wave = (int)((blockIdx.x * (size_t)blockDim.x + threadIdx.x) >> 6);
    int lane = threadIdx.x & 63;
    if (wave >= n) return;
    float2 v = *(const float2*)(h + (size_t)wave * ND + lane * 2);
    float2 w = *(const float2*)(Wlin + lane * 2);
    float s = v.x * w.x + v.y * w.y;
#pragma unroll
    for (int off = 32; off > 0; off >>= 1) s += __shfl_down(s, off);
    if (lane == 0) out[wave] = s + blin[0];
}

extern "C" void kernel_launch(void* const* d_in, const int* in_sizes, int n_in,
                              void* d_out, int out_size, void* d_ws, size_t ws_size,
                              hipStream_t stream) {
    const float* x    = (const float*)d_in[0];
    const int*   edge = (const int*)d_in[1];    // [2, E]
    const float* W1l  = (const float*)d_in[2];
    const float* b1   = (const float*)d_in[3];
    const float* W1r  = (const float*)d_in[4];
    const float* W2l  = (const float*)d_in[5];
    const float* b2   = (const float*)d_in[6];
    const float* W2r  = (const float*)d_in[7];
    const float* Wlin = (const float*)d_in[8];
    const float* blin = (const float*)d_in[9];
    float* out = (float*)d_out;

    int n = out_size;               // 100000 nodes
    int E = in_sizes[1] / 2;        // 640000 edges
    (void)n_in; (void)ws_size;

    char* ws = (char*)d_ws;
    size_t off = 0;
    auto take = [&](size_t bytes) -> char* {
        char* p = ws + off;
        off += (bytes + 255) & ~(size_t)255;
        return p;
    };
    int* deg    = (int*)take((size_t)n * 4);
    int* start  = (int*)take((size_t)n * 4);
    int* fill   = (int*)take((size_t)n * 4);
    int* cursor = (int*)take(256);
    int* esrc   = (int*)take((size_t)E * 4);
    float* bufA = (float*)take((size_t)n * ND * 4);
    float* bufB = (float*)take((size_t)n * ND * 4);
    unsigned short* Wt1 = (unsigned short*)take((size_t)ND * KTOT * 2);
    unsigned short* Wt2 = (unsigned short*)take((size_t)ND * KTOT * 2);

    hipMemsetAsync(deg, 0, (size_t)n * 4, stream);
    hipMemsetAsync(cursor, 0, 4, stream);

    const int* esrc_in = edge;       // row 0: src
    const int* edst_in = edge + E;   // row 1: dst

    k_count<<<(E + 255) / 256, 256, 0, stream>>>(edst_in, deg, E);
    k_offsets<<<(n + 255) / 256, 256, 0, stream>>>(deg, start, fill, cursor, n);
    k_scatter<<<(E + 255) / 256, 256, 0, stream>>>(esrc_in, edst_in, fill, esrc, E);
    k_prepw<<<128, 256, 0, stream>>>(W1l, W1r, Wt1);
    k_prepw<<<128, 256, 0, stream>>>(W2l, W2r, Wt2);

    int aggBlocks  = (n + 3) / 4;        // 4 waves (nodes) per 256-thread block
    int gemmBlocks = (n + 127) / 128;

    // layer 1
    k_aggregate<<<aggBlocks, 256, 0, stream>>>(x, bufA, start, deg, esrc, n);
    k_layer_mfma<<<gemmBlocks, 256, 0, stream>>>(bufA, x, Wt1, b1, bufB, n, 1);
    // layer 2
    k_aggregate<<<aggBlocks, 256, 0, stream>>>(bufB, bufA, start, deg, esrc, n);
    k_layer_mfma<<<gemmBlocks, 256, 0, stream>>>(bufA, bufB, Wt2, b2, bufA, n, 1);
    // head
    k_head<<<aggBlocks, 256, 0, stream>>>(bufA, Wlin, blin, out, n);
}

// Round 3
// 313.870 us; speedup vs baseline: 1.7988x; 1.3197x over previous
//
#include <hip/hip_runtime.h>
#include <hip/hip_bf16.h>

// GraphSAGE 2-layer + linear head, N=100000, d=h=128, E=640000.
// R3: full bf16 activation pipeline.
//   x -> xbf (bf16) -> agg(bf16 gather, fp32 sum) -> MFMA GEMM (bf16 in/out)
//   -> agg -> GEMM -> head. Gather traffic halves (256 B/row), GEMM staging
//   is a pure copy (no f2bf), epilogue writes bf16.

#define ND 128          // feature dim
#define KTOT 256        // concat K ([agg | self])
#define ASTRIDE 40      // 32 + 8 pad (shorts)

typedef __bf16 bf16x8 __attribute__((ext_vector_type(8)));
typedef float floatx16 __attribute__((ext_vector_type(16)));

__device__ inline unsigned short f2bf(float f) {
    union { float f; unsigned u; } v; v.f = f;
    unsigned r = v.u + 0x7fffu + ((v.u >> 16) & 1u);   // RTNE
    return (unsigned short)(r >> 16);
}
__device__ inline float bf_lo(unsigned u) { return __uint_as_float(u << 16); }
__device__ inline float bf_hi(unsigned u) { return __uint_as_float(u & 0xffff0000u); }

// ---------------- CSR build ----------------
__global__ void k_count(const int* __restrict__ dst, int* __restrict__ deg, int E) {
    int e = blockIdx.x * blockDim.x + threadIdx.x;
    if (e < E) atomicAdd(&deg[dst[e]], 1);
}

__global__ void k_offsets(const int* __restrict__ deg, int* __restrict__ start,
                          int* __restrict__ fill, int* __restrict__ cursor, int n) {
    int i = blockIdx.x * blockDim.x + threadIdx.x;
    int lane = threadIdx.x & 63;
    int d = (i < n) ? deg[i] : 0;
    int v = d;
#pragma unroll
    for (int off = 1; off < 64; off <<= 1) {
        int t = __shfl_up(v, off);
        if (lane >= off) v += t;
    }
    int total = __shfl(v, 63);
    int base = 0;
    if (lane == 0) base = atomicAdd(cursor, total);
    base = __shfl(base, 0);
    if (i < n) {
        int s = base + v - d;   // exclusive
        start[i] = s;
        fill[i] = s;
    }
}

__global__ void k_scatter(const int* __restrict__ src, const int* __restrict__ dst,
                          int* __restrict__ fill, int* __restrict__ esrc, int E) {
    int e = blockIdx.x * blockDim.x + threadIdx.x;
    if (e < E) {
        int p = atomicAdd(&fill[dst[e]], 1);
        esrc[p] = src[e];
    }
}

// ---------------- fp32 -> bf16 convert (8 elems/thread) ----------------
__global__ void k_tobf(const float* __restrict__ in, unsigned short* __restrict__ out,
                       int nElems) {
    int i = (blockIdx.x * blockDim.x + threadIdx.x) * 8;
    if (i >= nElems) return;
    float4 a = *(const float4*)(in + i);
    float4 b = *(const float4*)(in + i + 4);
    uint4 r;
    r.x = (unsigned)f2bf(a.x) | ((unsigned)f2bf(a.y) << 16);
    r.y = (unsigned)f2bf(a.z) | ((unsigned)f2bf(a.w) << 16);
    r.z = (unsigned)f2bf(b.x) | ((unsigned)f2bf(b.y) << 16);
    r.w = (unsigned)f2bf(b.z) | ((unsigned)f2bf(b.w) << 16);
    *(uint4*)(out + i) = r;
}

// ---------------- mean aggregation: half-wave (32 lanes) per node ----------------
// Row = 256 B bf16 = 32 lanes x uint2. Unroll-2 over neighbors for MLP.
__global__ void k_aggregate_bf(const unsigned short* __restrict__ feat,
                               unsigned short* __restrict__ out,
                               const int* __restrict__ start, const int* __restrict__ deg,
                               const int* __restrict__ esrc, int n) {
    int node = (int)((blockIdx.x * (size_t)blockDim.x + threadIdx.x) >> 5);
    int l = threadIdx.x & 31;
    if (node >= n) return;
    int s = start[node];
    int d = deg[node];
    float a0 = 0, a1 = 0, a2 = 0, a3 = 0;
    float c0 = 0, c1 = 0, c2 = 0, c3 = 0;
    int j = 0;
    for (; j + 2 <= d; j += 2) {
        int s0 = esrc[s + j];
        int s1 = esrc[s + j + 1];
        uint2 v0 = ((const uint2*)(feat + (size_t)s0 * ND))[l];
        uint2 v1 = ((const uint2*)(feat + (size_t)s1 * ND))[l];
        a0 += bf_lo(v0.x); a1 += bf_hi(v0.x); a2 += bf_lo(v0.y); a3 += bf_hi(v0.y);
        c0 += bf_lo(v1.x); c1 += bf_hi(v1.x); c2 += bf_lo(v1.y); c3 += bf_hi(v1.y);
    }
    if (j < d) {
        int s0 = esrc[s + j];
        uint2 v0 = ((const uint2*)(feat + (size_t)s0 * ND))[l];
        a0 += bf_lo(v0.x); a1 += bf_hi(v0.x); a2 += bf_lo(v0.y); a3 += bf_hi(v0.y);
    }
    a0 += c0; a1 += c1; a2 += c2; a3 += c3;
    float inv = 1.0f / (float)max(d, 1);
    uint2 r;
    r.x = (unsigned)f2bf(a0 * inv) | ((unsigned)f2bf(a1 * inv) << 16);
    r.y = (unsigned)f2bf(a2 * inv) | ((unsigned)f2bf(a3 * inv) << 16);
    ((uint2*)(out + (size_t)node * ND))[l] = r;
}

// ---------------- weight prep: Wt[n][k] bf16 from [Wl;Wr] fp32 [k][n] ----------------
__global__ void k_prepw(const float* __restrict__ Wl, const float* __restrict__ Wr,
                        unsigned short* __restrict__ Wt) {
    int idx = blockIdx.x * blockDim.x + threadIdx.x;   // 0..32767
    int nn = idx >> 8;       // output col
    int kk = idx & 255;      // concat K
    float v = (kk < 128) ? Wl[(size_t)kk * ND + nn] : Wr[(size_t)(kk - 128) * ND + nn];
    Wt[(size_t)nn * KTOT + kk] = f2bf(v);
}

// ---------------- MFMA GEMM layer (bf16 in, bf16 out) ----------------
// out[m0:m0+128, :] = relu([A0|A1] @ Wt^T + bias), K=256.
// 256 threads = 4 waves in 2x2; each wave 2x2 tiles of 32x32x16 MFMA.
__launch_bounds__(256, 2)
__global__ void k_layer_mfma(const unsigned short* __restrict__ A0,
                             const unsigned short* __restrict__ A1,
                             const unsigned short* __restrict__ Wt,
                             const float* __restrict__ bias,
                             unsigned short* __restrict__ out,
                             int n, int do_relu) {
    __shared__ __align__(16) unsigned short As[128 * ASTRIDE];
    __shared__ __align__(16) unsigned short Bs[128 * ASTRIDE];
    const int t = threadIdx.x;
    const int m0 = blockIdx.x * 128;
    const int wave = t >> 6, lane = t & 63;
    const int l31 = lane & 31, lhalf = lane >> 5;
    const int wm = (wave >> 1) * 64;
    const int wn = (wave & 1) * 64;

    floatx16 acc[2][2];
#pragma unroll
    for (int i = 0; i < 2; ++i)
#pragma unroll
        for (int j = 0; j < 2; ++j) acc[i][j] = (floatx16)0.0f;

    const int srow = t >> 1;           // staging row 0..127
    const int skid = (t & 1) * 16;     // staging k offset 0/16

    for (int kc = 0; kc < 8; ++kc) {
        const int k0 = kc * 32;
        // --- stage A chunk: pure bf16 copy ---
        {
            const unsigned short* base = (k0 < 128) ? A0 : A1;
            const int col = (k0 & 127) + skid;
            const int grow = m0 + srow;
            int4 w0 = {0, 0, 0, 0}, w1 = {0, 0, 0, 0};
            if (grow < n) {
                const int4* p = (const int4*)(base + (size_t)grow * ND + col);
                w0 = p[0]; w1 = p[1];
            }
            int4* q = (int4*)&As[srow * ASTRIDE + skid];
            q[0] = w0; q[1] = w1;
        }
        // --- stage B chunk ---
        {
            const int4* p = (const int4*)(Wt + (size_t)srow * KTOT + k0 + skid);
            int4* q = (int4*)&Bs[srow * ASTRIDE + skid];
            q[0] = p[0];
            q[1] = p[1];
        }
        __syncthreads();
        bf16x8 af[2][2], bfr[2][2];
#pragma unroll
        for (int mi = 0; mi < 2; ++mi)
#pragma unroll
            for (int ks = 0; ks < 2; ++ks)
                af[mi][ks] = *(const bf16x8*)&As[(wm + mi * 32 + l31) * ASTRIDE + ks * 16 + lhalf * 8];
#pragma unroll
        for (int ni = 0; ni < 2; ++ni)
#pragma unroll
            for (int ks = 0; ks < 2; ++ks)
                bfr[ni][ks] = *(const bf16x8*)&Bs[(wn + ni * 32 + l31) * ASTRIDE + ks * 16 + lhalf * 8];
#pragma unroll
        for (int mi = 0; mi < 2; ++mi)
#pragma unroll
            for (int ni = 0; ni < 2; ++ni) {
                acc[mi][ni] = __builtin_amdgcn_mfma_f32_32x32x16_bf16(af[mi][0], bfr[ni][0], acc[mi][ni], 0, 0, 0);
                acc[mi][ni] = __builtin_amdgcn_mfma_f32_32x32x16_bf16(af[mi][1], bfr[ni][1], acc[mi][ni], 0, 0, 0);
            }
        __syncthreads();
    }
    // --- epilogue: C/D layout col=lane&31, row=(reg&3)+8*(reg>>2)+4*(lane>>5) ---
#pragma unroll
    for (int mi = 0; mi < 2; ++mi)
#pragma unroll
        for (int ni = 0; ni < 2; ++ni) {
            const int c = wn + ni * 32 + l31;
            const float bv = bias[c];
#pragma unroll
            for (int r8 = 0; r8 < 4; ++r8)
#pragma unroll
                for (int r4 = 0; r4 < 4; ++r4) {
                    const int reg = r8 * 4 + r4;
                    const int row = m0 + wm + mi * 32 + lhalf * 4 + r4 + r8 * 8;
                    if (row < n) {
                        float v = acc[mi][ni][reg] + bv;
                        if (do_relu) v = fmaxf(v, 0.f);
                        out[(size_t)row * ND + c] = f2bf(v);
                    }
                }
        }
}

// ---------------- head: half-wave per node, bf16 h ----------------
__global__ void k_head(const unsigned short* __restrict__ h, const float* __restrict__ Wlin,
                       const float* __restrict__ blin, float* __restrict__ out, int n) {
    int node = (int)((blockIdx.x * (size_t)blockDim.x + threadIdx.x) >> 5);
    int l = threadIdx.x & 31;
    if (node >= n) return;
    uint2 hv = ((const uint2*)(h + (size_t)node * ND))[l];
    float4 w = ((const float4*)Wlin)[l];
    float s = bf_lo(hv.x) * w.x + bf_hi(hv.x) * w.y + bf_lo(hv.y) * w.z + bf_hi(hv.y) * w.w;
#pragma unroll
    for (int off = 16; off > 0; off >>= 1) s += __shfl_down(s, off);
    if (l == 0) out[node] = s + blin[0];
}

extern "C" void kernel_launch(void* const* d_in, const int* in_sizes, int n_in,
                              void* d_out, int out_size, void* d_ws, size_t ws_size,
                              hipStream_t stream) {
    const float* x    = (const float*)d_in[0];
    const int*   edge = (const int*)d_in[1];    // [2, E]
    const float* W1l  = (const float*)d_in[2];
    const float* b1   = (const float*)d_in[3];
    const float* W1r  = (const float*)d_in[4];
    const float* W2l  = (const float*)d_in[5];
    const float* b2   = (const float*)d_in[6];
    const float* W2r  = (const float*)d_in[7];
    const float* Wlin = (const float*)d_in[8];
    const float* blin = (const float*)d_in[9];
    float* out = (float*)d_out;

    int n = out_size;               // 100000 nodes
    int E = in_sizes[1] / 2;        // 640000 edges
    (void)n_in; (void)ws_size;

    char* ws = (char*)d_ws;
    size_t off = 0;
    auto take = [&](size_t bytes) -> char* {
        char* p = ws + off;
        off += (bytes + 255) & ~(size_t)255;
        return p;
    };
    int* deg    = (int*)take((size_t)n * 4);
    int* start  = (int*)take((size_t)n * 4);
    int* fill   = (int*)take((size_t)n * 4);
    int* cursor = (int*)take(256);
    int* esrc   = (int*)take((size_t)E * 4);
    unsigned short* xbf  = (unsigned short*)take((size_t)n * ND * 2);
    unsigned short* h1bf = (unsigned short*)take((size_t)n * ND * 2);
    unsigned short* agbf = (unsigned short*)take((size_t)n * ND * 2);
    unsigned short* Wt1  = (unsigned short*)take((size_t)ND * KTOT * 2);
    unsigned short* Wt2  = (unsigned short*)take((size_t)ND * KTOT * 2);

    hipMemsetAsync(deg, 0, (size_t)n * 4, stream);
    hipMemsetAsync(cursor, 0, 4, stream);

    const int* esrc_in = edge;       // row 0: src
    const int* edst_in = edge + E;   // row 1: dst

    k_count<<<(E + 255) / 256, 256, 0, stream>>>(edst_in, deg, E);
    k_offsets<<<(n + 255) / 256, 256, 0, stream>>>(deg, start, fill, cursor, n);
    k_scatter<<<(E + 255) / 256, 256, 0, stream>>>(esrc_in, edst_in, fill, esrc, E);
    k_prepw<<<128, 256, 0, stream>>>(W1l, W1r, Wt1);
    k_prepw<<<128, 256, 0, stream>>>(W2l, W2r, Wt2);
    k_tobf<<<(n * ND / 8 + 255) / 256, 256, 0, stream>>>(x, xbf, n * ND);

    int aggBlocks  = (n + 7) / 8;        // 8 nodes (half-waves) per 256-thread block
    int gemmBlocks = (n + 127) / 128;

    // layer 1
    k_aggregate_bf<<<aggBlocks, 256, 0, stream>>>(xbf, agbf, start, deg, esrc, n);
    k_layer_mfma<<<gemmBlocks, 256, 0, stream>>>(agbf, xbf, Wt1, b1, h1bf, n, 1);
    // layer 2 (out = agbf in-place: block writes only rows it fully consumed)
    k_aggregate_bf<<<aggBlocks, 256, 0, stream>>>(h1bf, agbf, start, deg, esrc, n);
    k_layer_mfma<<<gemmBlocks, 256, 0, stream>>>(agbf, h1bf, Wt2, b2, agbf, n, 1);
    // head
    k_head<<<aggBlocks, 256, 0, stream>>>(agbf, Wlin, blin, out, n);
}

// Round 4
// 294.083 us; speedup vs baseline: 1.9198x; 1.0673x over previous
//
#include <hip/hip_runtime.h>
#include <hip/hip_bf16.h>

// GraphSAGE 2-layer + linear head, N=100000, d=h=128, E=640000.
// R4: head fused into layer-2 GEMM epilogue (h2 never materialized);
//     aggregation gather unrolled 4x for memory-level parallelism;
//     x->bf16 convert + both weight preps merged into one dispatch.

#define ND 128          // feature dim
#define KTOT 256        // concat K ([agg | self])
#define ASTRIDE 40      // 32 + 8 pad (shorts)

typedef __bf16 bf16x8 __attribute__((ext_vector_type(8)));
typedef float floatx16 __attribute__((ext_vector_type(16)));

__device__ inline unsigned short f2bf(float f) {
    union { float f; unsigned u; } v; v.f = f;
    unsigned r = v.u + 0x7fffu + ((v.u >> 16) & 1u);   // RTNE
    return (unsigned short)(r >> 16);
}
__device__ inline float bf_lo(unsigned u) { return __uint_as_float(u << 16); }
__device__ inline float bf_hi(unsigned u) { return __uint_as_float(u & 0xffff0000u); }

// ---------------- CSR build ----------------
__global__ void k_count(const int* __restrict__ dst, int* __restrict__ deg, int E) {
    int e = blockIdx.x * blockDim.x + threadIdx.x;
    if (e < E) atomicAdd(&deg[dst[e]], 1);
}

__global__ void k_offsets(const int* __restrict__ deg, int* __restrict__ start,
                          int* __restrict__ fill, int* __restrict__ cursor, int n) {
    int i = blockIdx.x * blockDim.x + threadIdx.x;
    int lane = threadIdx.x & 63;
    int d = (i < n) ? deg[i] : 0;
    int v = d;
#pragma unroll
    for (int off = 1; off < 64; off <<= 1) {
        int t = __shfl_up(v, off);
        if (lane >= off) v += t;
    }
    int total = __shfl(v, 63);
    int base = 0;
    if (lane == 0) base = atomicAdd(cursor, total);
    base = __shfl(base, 0);
    if (i < n) {
        int s = base + v - d;   // exclusive
        start[i] = s;
        fill[i] = s;
    }
}

__global__ void k_scatter(const int* __restrict__ src, const int* __restrict__ dst,
                          int* __restrict__ fill, int* __restrict__ esrc, int E) {
    int e = blockIdx.x * blockDim.x + threadIdx.x;
    if (e < E) {
        int p = atomicAdd(&fill[dst[e]], 1);
        esrc[p] = src[e];
    }
}

// ---------------- merged prep: x->bf16 + Wt1 + Wt2 ----------------
// blocks [0, xBlocks): convert x; [xBlocks, xBlocks+128): Wt1; next 128: Wt2.
__global__ void k_prep(const float* __restrict__ x, unsigned short* __restrict__ xbf,
                       int nElems, int xBlocks,
                       const float* __restrict__ W1l, const float* __restrict__ W1r,
                       unsigned short* __restrict__ Wt1,
                       const float* __restrict__ W2l, const float* __restrict__ W2r,
                       unsigned short* __restrict__ Wt2) {
    int b = blockIdx.x;
    if (b < xBlocks) {
        int i = (b * 256 + threadIdx.x) * 8;
        if (i >= nElems) return;
        float4 a = *(const float4*)(x + i);
        float4 c = *(const float4*)(x + i + 4);
        uint4 r;
        r.x = (unsigned)f2bf(a.x) | ((unsigned)f2bf(a.y) << 16);
        r.y = (unsigned)f2bf(a.z) | ((unsigned)f2bf(a.w) << 16);
        r.z = (unsigned)f2bf(c.x) | ((unsigned)f2bf(c.y) << 16);
        r.w = (unsigned)f2bf(c.z) | ((unsigned)f2bf(c.w) << 16);
        *(uint4*)(xbf + i) = r;
    } else {
        int wb = b - xBlocks;
        const float* Wl = (wb < 128) ? W1l : W2l;
        const float* Wr = (wb < 128) ? W1r : W2r;
        unsigned short* Wt = (wb < 128) ? Wt1 : Wt2;
        int idx = (wb & 127) * 256 + threadIdx.x;   // 0..32767
        int nn = idx >> 8;       // output col
        int kk = idx & 255;      // concat K
        float v = (kk < 128) ? Wl[(size_t)kk * ND + nn] : Wr[(size_t)(kk - 128) * ND + nn];
        Wt[(size_t)nn * KTOT + kk] = f2bf(v);
    }
}

// ---------------- mean aggregation: half-wave (32 lanes) per node, unroll-4 ----------------
__global__ void k_aggregate_bf(const unsigned short* __restrict__ feat,
                               unsigned short* __restrict__ out,
                               const int* __restrict__ start, const int* __restrict__ deg,
                               const int* __restrict__ esrc, int n) {
    int node = (int)((blockIdx.x * (size_t)blockDim.x + threadIdx.x) >> 5);
    int l = threadIdx.x & 31;
    if (node >= n) return;
    int s = start[node];
    int d = deg[node];
    float4 A = {0,0,0,0}, B = {0,0,0,0}, C = {0,0,0,0}, D = {0,0,0,0};
    int j = 0;
    for (; j + 4 <= d; j += 4) {
        int s0 = esrc[s + j], s1 = esrc[s + j + 1];
        int s2 = esrc[s + j + 2], s3 = esrc[s + j + 3];
        uint2 v0 = ((const uint2*)(feat + (size_t)s0 * ND))[l];
        uint2 v1 = ((const uint2*)(feat + (size_t)s1 * ND))[l];
        uint2 v2 = ((const uint2*)(feat + (size_t)s2 * ND))[l];
        uint2 v3 = ((const uint2*)(feat + (size_t)s3 * ND))[l];
        A.x += bf_lo(v0.x); A.y += bf_hi(v0.x); A.z += bf_lo(v0.y); A.w += bf_hi(v0.y);
        B.x += bf_lo(v1.x); B.y += bf_hi(v1.x); B.z += bf_lo(v1.y); B.w += bf_hi(v1.y);
        C.x += bf_lo(v2.x); C.y += bf_hi(v2.x); C.z += bf_lo(v2.y); C.w += bf_hi(v2.y);
        D.x += bf_lo(v3.x); D.y += bf_hi(v3.x); D.z += bf_lo(v3.y); D.w += bf_hi(v3.y);
    }
    for (; j < d; ++j) {
        int s0 = esrc[s + j];
        uint2 v0 = ((const uint2*)(feat + (size_t)s0 * ND))[l];
        A.x += bf_lo(v0.x); A.y += bf_hi(v0.x); A.z += bf_lo(v0.y); A.w += bf_hi(v0.y);
    }
    A.x += B.x + C.x + D.x; A.y += B.y + C.y + D.y;
    A.z += B.z + C.z + D.z; A.w += B.w + C.w + D.w;
    float inv = 1.0f / (float)max(d, 1);
    uint2 r;
    r.x = (unsigned)f2bf(A.x * inv) | ((unsigned)f2bf(A.y * inv) << 16);
    r.y = (unsigned)f2bf(A.z * inv) | ((unsigned)f2bf(A.w * inv) << 16);
    ((uint2*)(out + (size_t)node * ND))[l] = r;
}

// ---------------- MFMA GEMM layer 1 (bf16 in, bf16 out) ----------------
__launch_bounds__(256, 2)
__global__ void k_layer_mfma(const unsigned short* __restrict__ A0,
                             const unsigned short* __restrict__ A1,
                             const unsigned short* __restrict__ Wt,
                             const float* __restrict__ bias,
                             unsigned short* __restrict__ out, int n) {
    __shared__ __align__(16) unsigned short As[128 * ASTRIDE];
    __shared__ __align__(16) unsigned short Bs[128 * ASTRIDE];
    const int t = threadIdx.x;
    const int m0 = blockIdx.x * 128;
    const int wave = t >> 6, lane = t & 63;
    const int l31 = lane & 31, lhalf = lane >> 5;
    const int wm = (wave >> 1) * 64;
    const int wn = (wave & 1) * 64;

    floatx16 acc[2][2];
#pragma unroll
    for (int i = 0; i < 2; ++i)
#pragma unroll
        for (int j = 0; j < 2; ++j) acc[i][j] = (floatx16)0.0f;

    const int srow = t >> 1;
    const int skid = (t & 1) * 16;

    for (int kc = 0; kc < 8; ++kc) {
        const int k0 = kc * 32;
        {
            const unsigned short* base = (k0 < 128) ? A0 : A1;
            const int col = (k0 & 127) + skid;
            const int grow = m0 + srow;
            int4 w0 = {0, 0, 0, 0}, w1 = {0, 0, 0, 0};
            if (grow < n) {
                const int4* p = (const int4*)(base + (size_t)grow * ND + col);
                w0 = p[0]; w1 = p[1];
            }
            int4* q = (int4*)&As[srow * ASTRIDE + skid];
            q[0] = w0; q[1] = w1;
        }
        {
            const int4* p = (const int4*)(Wt + (size_t)srow * KTOT + k0 + skid);
            int4* q = (int4*)&Bs[srow * ASTRIDE + skid];
            q[0] = p[0]; q[1] = p[1];
        }
        __syncthreads();
        bf16x8 af[2][2], bfr[2][2];
#pragma unroll
        for (int mi = 0; mi < 2; ++mi)
#pragma unroll
            for (int ks = 0; ks < 2; ++ks)
                af[mi][ks] = *(const bf16x8*)&As[(wm + mi * 32 + l31) * ASTRIDE + ks * 16 + lhalf * 8];
#pragma unroll
        for (int ni = 0; ni < 2; ++ni)
#pragma unroll
            for (int ks = 0; ks < 2; ++ks)
                bfr[ni][ks] = *(const bf16x8*)&Bs[(wn + ni * 32 + l31) * ASTRIDE + ks * 16 + lhalf * 8];
#pragma unroll
        for (int mi = 0; mi < 2; ++mi)
#pragma unroll
            for (int ni = 0; ni < 2; ++ni) {
                acc[mi][ni] = __builtin_amdgcn_mfma_f32_32x32x16_bf16(af[mi][0], bfr[ni][0], acc[mi][ni], 0, 0, 0);
                acc[mi][ni] = __builtin_amdgcn_mfma_f32_32x32x16_bf16(af[mi][1], bfr[ni][1], acc[mi][ni], 0, 0, 0);
            }
        __syncthreads();
    }
    // epilogue: relu + bf16 store. C/D: col=lane&31, row=(reg&3)+8*(reg>>2)+4*(lane>>5)
#pragma unroll
    for (int mi = 0; mi < 2; ++mi)
#pragma unroll
        for (int ni = 0; ni < 2; ++ni) {
            const int c = wn + ni * 32 + l31;
            const float bv = bias[c];
#pragma unroll
            for (int reg = 0; reg < 16; ++reg) {
                const int row = m0 + wm + mi * 32 + lhalf * 4 + (reg & 3) + 8 * (reg >> 2);
                if (row < n) {
                    float v = fmaxf(acc[mi][ni][reg] + bv, 0.f);
                    out[(size_t)row * ND + c] = f2bf(v);
                }
            }
        }
}

// ---------------- MFMA GEMM layer 2 + fused head ----------------
// h2 = relu([A0|A1]@Wt^T + bias) computed in-register; out[row] = dot(h2,Wlin)+blin.
__launch_bounds__(256, 2)
__global__ void k_layer2_head(const unsigned short* __restrict__ A0,
                              const unsigned short* __restrict__ A1,
                              const unsigned short* __restrict__ Wt,
                              const float* __restrict__ bias,
                              const float* __restrict__ Wlin,
                              const float* __restrict__ blin,
                              float* __restrict__ out, int n) {
    __shared__ __align__(16) unsigned short As[128 * ASTRIDE];
    __shared__ __align__(16) unsigned short Bs[128 * ASTRIDE];
    __shared__ float part[128][2];
    const int t = threadIdx.x;
    const int m0 = blockIdx.x * 128;
    const int wave = t >> 6, lane = t & 63;
    const int l31 = lane & 31, lhalf = lane >> 5;
    const int wm = (wave >> 1) * 64;
    const int wn = (wave & 1) * 64;

    floatx16 acc[2][2];
#pragma unroll
    for (int i = 0; i < 2; ++i)
#pragma unroll
        for (int j = 0; j < 2; ++j) acc[i][j] = (floatx16)0.0f;

    const int srow = t >> 1;
    const int skid = (t & 1) * 16;

    for (int kc = 0; kc < 8; ++kc) {
        const int k0 = kc * 32;
        {
            const unsigned short* base = (k0 < 128) ? A0 : A1;
            const int col = (k0 & 127) + skid;
            const int grow = m0 + srow;
            int4 w0 = {0, 0, 0, 0}, w1 = {0, 0, 0, 0};
            if (grow < n) {
                const int4* p = (const int4*)(base + (size_t)grow * ND + col);
                w0 = p[0]; w1 = p[1];
            }
            int4* q = (int4*)&As[srow * ASTRIDE + skid];
            q[0] = w0; q[1] = w1;
        }
        {
            const int4* p = (const int4*)(Wt + (size_t)srow * KTOT + k0 + skid);
            int4* q = (int4*)&Bs[srow * ASTRIDE + skid];
            q[0] = p[0]; q[1] = p[1];
        }
        __syncthreads();
        bf16x8 af[2][2], bfr[2][2];
#pragma unroll
        for (int mi = 0; mi < 2; ++mi)
#pragma unroll
            for (int ks = 0; ks < 2; ++ks)
                af[mi][ks] = *(const bf16x8*)&As[(wm + mi * 32 + l31) * ASTRIDE + ks * 16 + lhalf * 8];
#pragma unroll
        for (int ni = 0; ni < 2; ++ni)
#pragma unroll
            for (int ks = 0; ks < 2; ++ks)
                bfr[ni][ks] = *(const bf16x8*)&Bs[(wn + ni * 32 + l31) * ASTRIDE + ks * 16 + lhalf * 8];
#pragma unroll
        for (int mi = 0; mi < 2; ++mi)
#pragma unroll
            for (int ni = 0; ni < 2; ++ni) {
                acc[mi][ni] = __builtin_amdgcn_mfma_f32_32x32x16_bf16(af[mi][0], bfr[ni][0], acc[mi][ni], 0, 0, 0);
                acc[mi][ni] = __builtin_amdgcn_mfma_f32_32x32x16_bf16(af[mi][1], bfr[ni][1], acc[mi][ni], 0, 0, 0);
            }
        __syncthreads();
    }
    // fused epilogue: p[reg] = sum_c relu(h2[row][c]) * Wlin[c], reduced across lanes.
#pragma unroll
    for (int mi = 0; mi < 2; ++mi) {
        float p[16];
#pragma unroll
        for (int reg = 0; reg < 16; ++reg) p[reg] = 0.f;
#pragma unroll
        for (int ni = 0; ni < 2; ++ni) {
            const int c = wn + ni * 32 + l31;
            const float bv = bias[c];
            const float wv = Wlin[c];
#pragma unroll
            for (int reg = 0; reg < 16; ++reg) {
                float v = fmaxf(acc[mi][ni][reg] + bv, 0.f);
                p[reg] += v * wv;
            }
        }
#pragma unroll
        for (int reg = 0; reg < 16; ++reg) {
            float v = p[reg];
            v += __shfl_xor(v, 1);
            v += __shfl_xor(v, 2);
            v += __shfl_xor(v, 4);
            v += __shfl_xor(v, 8);
            v += __shfl_xor(v, 16);
            if (l31 == 0) {
                int rl = wm + mi * 32 + lhalf * 4 + (reg & 3) + 8 * (reg >> 2);
                part[rl][wave & 1] = v;
            }
        }
    }
    __syncthreads();
    if (t < 128) {
        int row = m0 + t;
        if (row < n) out[row] = part[t][0] + part[t][1] + blin[0];
    }
}

extern "C" void kernel_launch(void* const* d_in, const int* in_sizes, int n_in,
                              void* d_out, int out_size, void* d_ws, size_t ws_size,
                              hipStream_t stream) {
    const float* x    = (const float*)d_in[0];
    const int*   edge = (const int*)d_in[1];    // [2, E]
    const float* W1l  = (const float*)d_in[2];
    const float* b1   = (const float*)d_in[3];
    const float* W1r  = (const float*)d_in[4];
    const float* W2l  = (const float*)d_in[5];
    const float* b2   = (const float*)d_in[6];
    const float* W2r  = (const float*)d_in[7];
    const float* Wlin = (const float*)d_in[8];
    const float* blin = (const float*)d_in[9];
    float* out = (float*)d_out;

    int n = out_size;               // 100000 nodes
    int E = in_sizes[1] / 2;        // 640000 edges
    (void)n_in; (void)ws_size;

    char* ws = (char*)d_ws;
    size_t off = 0;
    auto take = [&](size_t bytes) -> char* {
        char* p = ws + off;
        off += (bytes + 255) & ~(size_t)255;
        return p;
    };
    int* deg    = (int*)take((size_t)n * 4);
    int* start  = (int*)take((size_t)n * 4);
    int* fill   = (int*)take((size_t)n * 4);
    int* cursor = (int*)take(256);
    int* esrc   = (int*)take((size_t)E * 4);
    unsigned short* xbf  = (unsigned short*)take((size_t)n * ND * 2);
    unsigned short* h1bf = (unsigned short*)take((size_t)n * ND * 2);
    unsigned short* agbf = (unsigned short*)take((size_t)n * ND * 2);
    unsigned short* Wt1  = (unsigned short*)take((size_t)ND * KTOT * 2);
    unsigned short* Wt2  = (unsigned short*)take((size_t)ND * KTOT * 2);

    hipMemsetAsync(deg, 0, (size_t)n * 4, stream);
    hipMemsetAsync(cursor, 0, 4, stream);

    const int* esrc_in = edge;       // row 0: src
    const int* edst_in = edge + E;   // row 1: dst

    int xBlocks = (n * ND / 8 + 255) / 256;

    k_count<<<(E + 255) / 256, 256, 0, stream>>>(edst_in, deg, E);
    k_offsets<<<(n + 255) / 256, 256, 0, stream>>>(deg, start, fill, cursor, n);
    k_scatter<<<(E + 255) / 256, 256, 0, stream>>>(esrc_in, edst_in, fill, esrc, E);
    k_prep<<<xBlocks + 256, 256, 0, stream>>>(x, xbf, n * ND, xBlocks,
                                              W1l, W1r, Wt1, W2l, W2r, Wt2);

    int aggBlocks  = (n + 7) / 8;        // 8 nodes (half-waves) per 256-thread block
    int gemmBlocks = (n + 127) / 128;

    // layer 1
    k_aggregate_bf<<<aggBlocks, 256, 0, stream>>>(xbf, agbf, start, deg, esrc, n);
    k_layer_mfma<<<gemmBlocks, 256, 0, stream>>>(agbf, xbf, Wt1, b1, h1bf, n);
    // layer 2 + head (h2 never materialized)
    k_aggregate_bf<<<aggBlocks, 256, 0, stream>>>(h1bf, agbf, start, deg, esrc, n);
    k_layer2_head<<<gemmBlocks, 256, 0, stream>>>(agbf, h1bf, Wt2, b2, Wlin, blin, out, n);
}